// Round 7
// baseline (764.279 us; speedup 1.0000x reference)
//
#include <hip/hip_runtime.h>

typedef unsigned char u8;
typedef unsigned short u16;
typedef unsigned int u32;
typedef __attribute__((ext_vector_type(8))) short short8;
typedef __attribute__((ext_vector_type(4))) float f32x4;
typedef __attribute__((ext_vector_type(2))) float f32x2;

__device__ __forceinline__ float bf2f(u16 u) {
    return __uint_as_float(((u32)u) << 16);
}
__device__ __forceinline__ u16 f2bf(float f) {
    u32 u = __float_as_uint(f);
    u += 0x7fff + ((u >> 16) & 1);   // round-to-nearest-even
    return (u16)(u >> 16);
}
__device__ __forceinline__ u32 pack2(float a, float b) {
    return (u32)f2bf(a) | ((u32)f2bf(b) << 16);
}
// pack 4 floats -> 4 fp8 e4m3 in one u32
__device__ __forceinline__ u32 pk_fp8x4(float f0, float f1, float f2, float f3) {
    int w = __builtin_amdgcn_cvt_pk_fp8_f32(f0, f1, 0, false);
    w = __builtin_amdgcn_cvt_pk_fp8_f32(f2, f3, w, true);
    return (u32)w;
}
// accumulate 4 fp8 (one u32) into a[0..3]
__device__ __forceinline__ void acc4(float* a, u32 w) {
    f32x2 lo = __builtin_amdgcn_cvt_pk_f32_fp8((int)w, false);
    f32x2 hi = __builtin_amdgcn_cvt_pk_f32_fp8((int)w, true);
    a[0] += lo.x; a[1] += lo.y; a[2] += hi.x; a[3] += hi.y;
}
__device__ __forceinline__ void acc4m(float* a, u32 w, float m) {
    f32x2 lo = __builtin_amdgcn_cvt_pk_f32_fp8((int)w, false);
    f32x2 hi = __builtin_amdgcn_cvt_pk_f32_fp8((int)w, true);
    a[0] += m * lo.x; a[1] += m * lo.y; a[2] += m * hi.x; a[3] += m * hi.y;
}
__device__ __forceinline__ void acc16(float* a, uint4 v) {
    acc4(a + 0, v.x); acc4(a + 4, v.y); acc4(a + 8, v.z); acc4(a + 12, v.w);
}
__device__ __forceinline__ void acc16m(float* a, uint4 v, float m) {
    acc4m(a + 0, v.x, m); acc4m(a + 4, v.y, m); acc4m(a + 8, v.z, m); acc4m(a + 12, v.w, m);
}

// ---------------- conversions ----------------

// x fp32 -> xb bf16 [NPAD][256]  and  xq fp8 [NPAD][256]
__global__ void cvt_x_kernel(const float* __restrict__ x, u16* __restrict__ xb,
                             u32* __restrict__ xq, int n) {
    int i = blockIdx.x * 256 + threadIdx.x;   // group of 4 elements
    int row = i >> 6;
    ushort4 o;
    u32 q;
    if (row < n) {
        float4 v = ((const float4*)x)[i];
        o.x = f2bf(v.x); o.y = f2bf(v.y); o.z = f2bf(v.z); o.w = f2bf(v.w);
        q = pk_fp8x4(v.x, v.y, v.z, v.w);
    } else {
        o.x = o.y = o.z = o.w = 0;
        q = 0;
    }
    ((ushort4*)xb)[i] = o;
    xq[i] = q;
}

// h bf16 -> fp8 copy (8 feats per thread)
__global__ void cvt_h_kernel(const u16* __restrict__ hb, uint2* __restrict__ hq, int ngroups) {
    int j = blockIdx.x * 256 + threadIdx.x;
    if (j >= ngroups) return;
    uint4 v = ((const uint4*)hb)[j];
    float f0 = bf2f(v.x & 0xffff), f1 = bf2f(v.x >> 16);
    float f2 = bf2f(v.y & 0xffff), f3 = bf2f(v.y >> 16);
    float f4 = bf2f(v.z & 0xffff), f5 = bf2f(v.z >> 16);
    float f6 = bf2f(v.w & 0xffff), f7 = bf2f(v.w >> 16);
    uint2 o;
    o.x = pk_fp8x4(f0, f1, f2, f3);
    o.y = pk_fp8x4(f4, f5, f6, f7);
    hq[j] = o;
}

// wT layout: [layer][n=256][k=512] bf16, k-contiguous (A rows then B rows)
__global__ void cvt_w_kernel(const float* __restrict__ WA, const float* __restrict__ WB,
                             const float* __restrict__ As, const float* __restrict__ Bs,
                             u16* __restrict__ wT, int nlayers) {
    int i = blockIdx.x * 256 + threadIdx.x;
    const int per = 256 * 512;
    if (i >= nlayers * per) return;
    int l = i / per;
    int rem = i - l * per;
    int nn = rem >> 9;
    int k = rem & 511;
    const float* Aw = (l == 0) ? WA : As + (size_t)(l - 1) * 65536;
    const float* Bw = (l == 0) ? WB : Bs + (size_t)(l - 1) * 65536;
    float v = (k < 256) ? Aw[(size_t)k * 256 + nn] : Bw[(size_t)(k - 256) * 256 + nn];
    wT[i] = f2bf(v);
}

// ---------------- CSR build: two-level counting sort ----------------
// Requires N <= 65536; coarse bucket b covers nodes [b*256, b*256+256).

__global__ __launch_bounds__(256) void hist_kernel(const int* __restrict__ dst,
                                                   int* __restrict__ ccnt, int e, int nb) {
    __shared__ int h[256];
    int tid = threadIdx.x;
    h[tid] = 0;
    __syncthreads();
    int e0 = blockIdx.x * 4096;
#pragma unroll
    for (int j = 0; j < 16; ++j) {
        int i = e0 + j * 256 + tid;
        if (i < e) atomicAdd(&h[dst[i] >> 8], 1);
    }
    __syncthreads();
    if (tid < nb) {
        int v = h[tid];
        if (v) atomicAdd(&ccnt[tid], v);
    }
}

__global__ __launch_bounds__(256) void scan_coarse_kernel(const int* __restrict__ ccnt,
                                                          int* __restrict__ cbase,
                                                          int* __restrict__ rowptr,
                                                          int nb, int n, int e) {
    __shared__ int sh[256];
    int t = threadIdx.x;
    int v = (t < nb) ? ccnt[t] : 0;
    int x = v;
    sh[t] = x; __syncthreads();
    for (int o = 1; o < 256; o <<= 1) {
        int y = (t >= o) ? sh[t - o] : 0;
        __syncthreads();
        x += y; sh[t] = x; __syncthreads();
    }
    if (t < nb) cbase[t] = x - v;
    if (t == 0) { cbase[nb] = e; rowptr[n] = e; }
}

__global__ __launch_bounds__(256) void passA_kernel(const int* __restrict__ src,
                                                    const int* __restrict__ dst,
                                                    const int* __restrict__ cbase,
                                                    int* __restrict__ cfill,
                                                    u32* __restrict__ tmp, int e, int nb) {
    __shared__ int ph[256], pb[256], pr[256], cb[256];
    __shared__ u32 ed[4096];
    int tid = threadIdx.x;
    ph[tid] = 0; pr[tid] = 0;
    cb[tid] = (tid < nb) ? cbase[tid] : 0;
    __syncthreads();
    int e0 = blockIdx.x * 4096;
#pragma unroll
    for (int j = 0; j < 16; ++j) {
        int i = e0 + j * 256 + tid;
        u32 p = 0xFFFFFFFFu;
        if (i < e) {
            int d = dst[i];
            p = ((u32)d << 16) | (u32)src[i];
            atomicAdd(&ph[d >> 8], 1);
        }
        ed[j * 256 + tid] = p;
    }
    __syncthreads();
    pb[tid] = (tid < nb && ph[tid]) ? atomicAdd(&cfill[tid], ph[tid]) : 0;
    __syncthreads();
#pragma unroll
    for (int j = 0; j < 16; ++j) {
        u32 p = ed[j * 256 + tid];
        if (p != 0xFFFFFFFFu) {
            int bk = p >> 24;
            int r = atomicAdd(&pr[bk], 1);
            tmp[cb[bk] + pb[bk] + r] = p;
        }
    }
}

__global__ __launch_bounds__(256) void passB_kernel(const u32* __restrict__ tmp,
                                                    const int* __restrict__ cbase,
                                                    int* __restrict__ rowptr,
                                                    float* __restrict__ invd,
                                                    int* __restrict__ srcs, int n) {
    __shared__ int h[256], loc[256], cnt2[256], sh[256];
    int b = blockIdx.x;
    int tid = threadIdx.x;
    int base = cbase[b];
    int cnt = cbase[b + 1] - base;
    int node0 = b << 8;
    h[tid] = 0; cnt2[tid] = 0;
    __syncthreads();
    for (int i = tid; i < cnt; i += 256)
        atomicAdd(&h[(tmp[base + i] >> 16) & 255], 1);
    __syncthreads();
    int c = h[tid];
    int x = c;
    sh[tid] = x; __syncthreads();
    for (int o = 1; o < 256; o <<= 1) {
        int y = (tid >= o) ? sh[tid - o] : 0;
        __syncthreads();
        x += y; sh[tid] = x; __syncthreads();
    }
    loc[tid] = x - c;
    int node = node0 + tid;
    if (node < n) {
        rowptr[node] = base + x - c;
        invd[node] = 1.0f / (float)(c > 0 ? c : 1);
    }
    __syncthreads();
    for (int i = tid; i < cnt; i += 256) {
        u32 p = tmp[base + i];
        int ln = (p >> 16) & 255;
        int r = atomicAdd(&cnt2[ln], 1);
        srcs[base + loc[ln] + r] = (int)(p & 0xffffu);
    }
}

// ---------------- mean aggregation: one wave per node, fp8 gather, bf16 mean out ----------------

__global__ __launch_bounds__(256) void agg_kernel(const u8* __restrict__ q,
                                                  u16* __restrict__ mb,
                                                  const int* __restrict__ rowptr,
                                                  const int* __restrict__ srcs,
                                                  const float* __restrict__ invd,
                                                  int n, int npad) {
    int gw = (blockIdx.x * 256 + threadIdx.x) >> 6;
    int lane = threadIdx.x & 63;
    int qd = lane >> 4;          // edge slot within group of 4
    int fl = lane & 15;          // 16B chunk within fp8 row
    if (gw >= npad) return;
    u16* orow = mb + (size_t)gw * 256;
    if (gw >= n) {
        if (lane < 16) {
            uint4 z; z.x = z.y = z.z = z.w = 0;
            uint4* p = (uint4*)(orow + lane * 16);
            p[0] = z; p[1] = z;
        }
        return;
    }
    int beg = rowptr[gw], end = rowptr[gw + 1];
    float a[16];
#pragma unroll
    for (int i = 0; i < 16; ++i) a[i] = 0.f;
    for (int base = beg; base < end; base += 64) {
        int cnt = end - base;
        if (cnt > 64) cnt = 64;
        int el = (lane < cnt) ? srcs[base + lane] : 0;
        int t = 0;
        for (; 4 * t + 8 <= cnt; t += 2) {
            int s0 = __shfl(el, 4 * t + qd);
            int s1 = __shfl(el, 4 * t + 4 + qd);
            uint4 v0 = *(const uint4*)(q + (size_t)s0 * 256 + fl * 16);
            uint4 v1 = *(const uint4*)(q + (size_t)s1 * 256 + fl * 16);
            acc16(a, v0);
            acc16(a, v1);
        }
        for (; 4 * t < cnt; ++t) {
            int ei = 4 * t + qd;
            int sj = __shfl(el, ei & 63);
            float m = (ei < cnt) ? 1.0f : 0.0f;
            uint4 v = *(const uint4*)(q + (size_t)sj * 256 + fl * 16);
            acc16m(a, v, m);
        }
    }
#pragma unroll
    for (int i = 0; i < 16; ++i) {
        a[i] += __shfl_xor(a[i], 16);
        a[i] += __shfl_xor(a[i], 32);
    }
    if (lane < 16) {
        float sc = invd[gw];
        uint4 o0, o1;
        o0.x = pack2(a[0] * sc, a[1] * sc);
        o0.y = pack2(a[2] * sc, a[3] * sc);
        o0.z = pack2(a[4] * sc, a[5] * sc);
        o0.w = pack2(a[6] * sc, a[7] * sc);
        o1.x = pack2(a[8] * sc, a[9] * sc);
        o1.y = pack2(a[10] * sc, a[11] * sc);
        o1.z = pack2(a[12] * sc, a[13] * sc);
        o1.w = pack2(a[14] * sc, a[15] * sc);
        uint4* p = (uint4*)(orow + lane * 16);
        p[0] = o0; p[1] = o1;
    }
}

// ---------------- GEMM, bf16, LDS-resident B-quarter, barrier-free K-loop ----------------
// A = [mb | cur] bf16 [NPAD][256] row-major (k<256 from mb, k>=256 from cur).
// B = wT layer slice bf16 [n=256][k=512] k-contiguous; block (bid&3) holds output
// cols qtr*64..+64 in LDS (64 KB), XOR-swizzled: 16B slot s of row nn at phys s^nn
// -> 2-way max bank aliasing on both ds_write_b128 and ds_read_b128 (free).
// Each wave computes 16-row x 64-col tiles; A-frags direct from global (16x16B,
// issued up-front); 4 MFMA 16x16x32_bf16 per k-step; no barriers in the loop.
// fin: sigmoid, dot wo-quarter, wave-reduce, atomicAdd into pre-zeroed out.

__global__ __launch_bounds__(512, 4) void gemm_kernel(const u16* __restrict__ mb,
                                                      const u16* __restrict__ cur,
                                                      const u16* __restrict__ wT,
                                                      u16* __restrict__ hout,
                                                      const float* __restrict__ wo,
                                                      const float* __restrict__ bo,
                                                      float* __restrict__ out,
                                                      int n, int ntiles, int sig, int fin) {
    __shared__ u16 lB[64 * 512];   // 64 output cols x 512 k (bf16), swizzled
    int tid = threadIdx.x;
    int bid = blockIdx.x;
    int qtr = bid & 3;
    int w = tid >> 6;
    int lane = tid & 63;
    int lrow = lane & 15, quad = lane >> 4;
    int wslot = (bid >> 2) * 8 + w;
    int wstride = (gridDim.x >> 2) * 8;

    // stage B quarter once: 64 rows x 64 slots of 16B
    const u16* wsrc = wT + (size_t)qtr * 64 * 512;
#pragma unroll
    for (int i = tid; i < 64 * 64; i += 512) {
        int nn = i >> 6, s = i & 63;
        uint4 v = *(const uint4*)(wsrc + (size_t)nn * 512 + s * 8);
        *(uint4*)((u8*)lB + (size_t)nn * 1024 + ((s ^ nn) << 4)) = v;
    }
    __syncthreads();

    float bo0 = bo[0];
    for (int t = wslot; t < ntiles; t += wstride) {
        int r0 = t * 16;
        const u16* am = mb + (size_t)(r0 + lrow) * 256 + quad * 8;
        const u16* ac = cur + (size_t)(r0 + lrow) * 256 + quad * 8;
        short8 av[16];
#pragma unroll
        for (int ks = 0; ks < 8; ++ks) av[ks] = *(const short8*)(am + ks * 32);
#pragma unroll
        for (int ks = 0; ks < 8; ++ks) av[8 + ks] = *(const short8*)(ac + ks * 32);

        f32x4 acc[4] = {};
#pragma unroll
        for (int ks = 0; ks < 16; ++ks) {
#pragma unroll
            for (int ct = 0; ct < 4; ++ct) {
                int nn = ct * 16 + lrow;
                int slot = ks * 4 + quad;
                short8 b = *(const short8*)((const u8*)lB + (size_t)nn * 1024 + ((slot ^ nn) << 4));
                acc[ct] = __builtin_amdgcn_mfma_f32_16x16x32_bf16(av[ks], b, acc[ct], 0, 0, 0);
            }
        }

        if (!fin) {
#pragma unroll
            for (int ct = 0; ct < 4; ++ct) {
#pragma unroll
                for (int r = 0; r < 4; ++r) {
                    float v = acc[ct][r];
                    if (sig) v = 1.0f / (1.0f + __expf(-v));
                    int row = r0 + quad * 4 + r;
                    hout[(size_t)row * 256 + qtr * 64 + ct * 16 + lrow] = f2bf(v);
                }
            }
        } else {
            float wv[4];
#pragma unroll
            for (int ct = 0; ct < 4; ++ct) wv[ct] = wo[qtr * 64 + ct * 16 + lrow];
#pragma unroll
            for (int r = 0; r < 4; ++r) {
                float s = 0.f;
#pragma unroll
                for (int ct = 0; ct < 4; ++ct) {
                    float v = acc[ct][r];
                    v = 1.0f / (1.0f + __expf(-v));
                    s += v * wv[ct];
                }
                s += __shfl_xor(s, 1);
                s += __shfl_xor(s, 2);
                s += __shfl_xor(s, 4);
                s += __shfl_xor(s, 8);
                if (lrow == 0) {
                    int row = r0 + quad * 4 + r;
                    if (row < n) atomicAdd(&out[row], s + (qtr == 0 ? bo0 : 0.f));
                }
            }
        }
    }
}

// ---------------- launch ----------------

extern "C" void kernel_launch(void* const* d_in, const int* in_sizes, int n_in,
                              void* d_out, int out_size, void* d_ws, size_t ws_size,
                              hipStream_t stream) {
    const float* x  = (const float*)d_in[0];
    const int*   ei = (const int*)d_in[1];
    const float* WA = (const float*)d_in[2];
    const float* WB = (const float*)d_in[3];
    const float* As = (const float*)d_in[4];
    const float* Bs = (const float*)d_in[5];
    const float* Wo = (const float*)d_in[6];
    const float* bo = (const float*)d_in[7];
    float* out = (float*)d_out;

    const int H = 256;
    int N = in_sizes[0] / H;
    int E = in_sizes[1] / 2;
    int L = in_sizes[4] / (H * H);
    int NPAD = (N + 127) & ~127;
    int NB = (N + 255) >> 8;           // coarse buckets (requires N <= 65536)
    int ntiles = NPAD / 16;

    char* wsp = (char*)d_ws;
    size_t off = 0;
    auto alloc = [&](size_t b) { size_t o = off; off += (b + 255) & ~(size_t)255; return o; };
    int*   rowptr = (int*)(wsp + alloc((size_t)(NPAD + 1) * 4));
    int*   ccnt   = (int*)(wsp + alloc(1024));
    int*   cbase  = (int*)(wsp + alloc(1032 + 256));
    int*   cfill  = (int*)(wsp + alloc(1024));
    float* invd   = (float*)(wsp + alloc((size_t)NPAD * 4));
    int*   srcs   = (int*)(wsp + alloc((size_t)E * 4));
    u16*   xb     = (u16*)(wsp + alloc((size_t)NPAD * H * 2));
    u16*   h0     = (u16*)(wsp + alloc((size_t)NPAD * H * 2));
    u16*   h1     = (u16*)(wsp + alloc((size_t)NPAD * H * 2));
    u16*   mb     = (u16*)(wsp + alloc((size_t)NPAD * H * 2));
    u8*    xq     = (u8*)(wsp + alloc((size_t)NPAD * H));
    u8*    hq     = (u8*)(wsp + alloc((size_t)NPAD * H));
    u16*   wT     = (u16*)(wsp + alloc((size_t)(L + 1) * 512 * 256 * 2));
    // tmp (packed coarse-sorted edges) aliases mb: dead until first agg writes mb
    u32*   tmp    = (u32*)mb;

    const int* esrc = ei;
    const int* edst = ei + E;

    hipMemsetAsync(ccnt, 0, 1024, stream);
    hipMemsetAsync(cfill, 0, 1024, stream);
    hipMemsetAsync(out, 0, (size_t)N * 4, stream);

    int gridE = (E + 4095) / 4096;
    cvt_x_kernel<<<NPAD / 4, 256, 0, stream>>>(x, xb, (u32*)xq, N);
    cvt_w_kernel<<<((L + 1) * 512 * 256 + 255) / 256, 256, 0, stream>>>(WA, WB, As, Bs, wT, L + 1);
    hist_kernel<<<gridE, 256, 0, stream>>>(edst, ccnt, E, NB);
    scan_coarse_kernel<<<1, 256, 0, stream>>>(ccnt, cbase, rowptr, NB, N, E);
    passA_kernel<<<gridE, 256, 0, stream>>>(esrc, edst, cbase, cfill, tmp, E, NB);
    passB_kernel<<<NB, 256, 0, stream>>>(tmp, cbase, rowptr, invd, srcs, N);

    const u16* cur = xb;
    const u8*  curq = xq;
    for (int s = 0; s <= L; ++s) {
        int fin = (s == L) ? 1 : 0;
        u16* nxt = (s & 1) ? h1 : h0;
        agg_kernel<<<NPAD / 4, 256, 0, stream>>>(curq, mb, rowptr, srcs, invd, N, NPAD);
        gemm_kernel<<<512, 512, 0, stream>>>(mb, cur, wT + (size_t)s * 512 * 256, nxt,
                                             Wo, bo, out, N, ntiles, s > 0 ? 1 : 0, fin);
        if (!fin) {
            cvt_h_kernel<<<(N * 32 + 255) / 256, 256, 0, stream>>>(nxt, (uint2*)hq, N * 32);
            cur = nxt;
            curq = hq;
        }
    }
}

// Round 8
// 404.045 us; speedup vs baseline: 1.8916x; 1.8916x over previous
//
#include <hip/hip_runtime.h>

typedef unsigned char u8;
typedef unsigned short u16;
typedef unsigned int u32;
typedef __attribute__((ext_vector_type(8))) short short8;
typedef __attribute__((ext_vector_type(4))) float f32x4;
typedef __attribute__((ext_vector_type(2))) float f32x2;

__device__ __forceinline__ float bf2f(u16 u) {
    return __uint_as_float(((u32)u) << 16);
}
__device__ __forceinline__ u16 f2bf(float f) {
    u32 u = __float_as_uint(f);
    u += 0x7fff + ((u >> 16) & 1);   // round-to-nearest-even
    return (u16)(u >> 16);
}
__device__ __forceinline__ u32 pack2(float a, float b) {
    return (u32)f2bf(a) | ((u32)f2bf(b) << 16);
}
// pack 4 floats -> 4 fp8 e4m3 in one u32
__device__ __forceinline__ u32 pk_fp8x4(float f0, float f1, float f2, float f3) {
    int w = __builtin_amdgcn_cvt_pk_fp8_f32(f0, f1, 0, false);
    w = __builtin_amdgcn_cvt_pk_fp8_f32(f2, f3, w, true);
    return (u32)w;
}
__device__ __forceinline__ u8 f2fp8(float f) {
    return (u8)(__builtin_amdgcn_cvt_pk_fp8_f32(f, f, 0, false) & 0xff);
}
// accumulate 4 fp8 (one u32) into a[0..3]
__device__ __forceinline__ void acc4(float* a, u32 w) {
    f32x2 lo = __builtin_amdgcn_cvt_pk_f32_fp8((int)w, false);
    f32x2 hi = __builtin_amdgcn_cvt_pk_f32_fp8((int)w, true);
    a[0] += lo.x; a[1] += lo.y; a[2] += hi.x; a[3] += hi.y;
}
__device__ __forceinline__ void acc4m(float* a, u32 w, float m) {
    f32x2 lo = __builtin_amdgcn_cvt_pk_f32_fp8((int)w, false);
    f32x2 hi = __builtin_amdgcn_cvt_pk_f32_fp8((int)w, true);
    a[0] += m * lo.x; a[1] += m * lo.y; a[2] += m * hi.x; a[3] += m * hi.y;
}
__device__ __forceinline__ void acc16(float* a, uint4 v) {
    acc4(a + 0, v.x); acc4(a + 4, v.y); acc4(a + 8, v.z); acc4(a + 12, v.w);
}
__device__ __forceinline__ void acc16m(float* a, uint4 v, float m) {
    acc4m(a + 0, v.x, m); acc4m(a + 4, v.y, m); acc4m(a + 8, v.z, m); acc4m(a + 12, v.w, m);
}

// ---------------- conversions ----------------

// x fp32 -> xb bf16 [NPAD][256]  and  xq fp8 [NPAD][256]
__global__ void cvt_x_kernel(const float* __restrict__ x, u16* __restrict__ xb,
                             u32* __restrict__ xq, int n) {
    int i = blockIdx.x * 256 + threadIdx.x;   // group of 4 elements
    int row = i >> 6;
    ushort4 o;
    u32 q;
    if (row < n) {
        float4 v = ((const float4*)x)[i];
        o.x = f2bf(v.x); o.y = f2bf(v.y); o.z = f2bf(v.z); o.w = f2bf(v.w);
        q = pk_fp8x4(v.x, v.y, v.z, v.w);
    } else {
        o.x = o.y = o.z = o.w = 0;
        q = 0;
    }
    ((ushort4*)xb)[i] = o;
    xq[i] = q;
}

// wT layout: [layer][n=256][k=512] bf16, k-contiguous (A rows then B rows)
__global__ void cvt_w_kernel(const float* __restrict__ WA, const float* __restrict__ WB,
                             const float* __restrict__ As, const float* __restrict__ Bs,
                             u16* __restrict__ wT, int nlayers) {
    int i = blockIdx.x * 256 + threadIdx.x;
    const int per = 256 * 512;
    if (i >= nlayers * per) return;
    int l = i / per;
    int rem = i - l * per;
    int nn = rem >> 9;
    int k = rem & 511;
    const float* Aw = (l == 0) ? WA : As + (size_t)(l - 1) * 65536;
    const float* Bw = (l == 0) ? WB : Bs + (size_t)(l - 1) * 65536;
    float v = (k < 256) ? Aw[(size_t)k * 256 + nn] : Bw[(size_t)(k - 256) * 256 + nn];
    wT[i] = f2bf(v);
}

// ---------------- CSR build: two-level counting sort ----------------
// Requires N <= 65536; coarse bucket b covers nodes [b*256, b*256+256).

__global__ __launch_bounds__(256) void hist_kernel(const int* __restrict__ dst,
                                                   int* __restrict__ ccnt, int e, int nb) {
    __shared__ int h[256];
    int tid = threadIdx.x;
    h[tid] = 0;
    __syncthreads();
    int e0 = blockIdx.x * 4096;
#pragma unroll
    for (int j = 0; j < 16; ++j) {
        int i = e0 + j * 256 + tid;
        if (i < e) atomicAdd(&h[dst[i] >> 8], 1);
    }
    __syncthreads();
    if (tid < nb) {
        int v = h[tid];
        if (v) atomicAdd(&ccnt[tid], v);
    }
}

__global__ __launch_bounds__(256) void scan_coarse_kernel(const int* __restrict__ ccnt,
                                                          int* __restrict__ cbase,
                                                          int* __restrict__ rowptr,
                                                          int nb, int n, int e) {
    __shared__ int sh[256];
    int t = threadIdx.x;
    int v = (t < nb) ? ccnt[t] : 0;
    int x = v;
    sh[t] = x; __syncthreads();
    for (int o = 1; o < 256; o <<= 1) {
        int y = (t >= o) ? sh[t - o] : 0;
        __syncthreads();
        x += y; sh[t] = x; __syncthreads();
    }
    if (t < nb) cbase[t] = x - v;
    if (t == 0) { cbase[nb] = e; rowptr[n] = e; }
}

__global__ __launch_bounds__(256) void passA_kernel(const int* __restrict__ src,
                                                    const int* __restrict__ dst,
                                                    const int* __restrict__ cbase,
                                                    int* __restrict__ cfill,
                                                    u32* __restrict__ tmp, int e, int nb) {
    __shared__ int ph[256], pb[256], pr[256], cb[256];
    __shared__ u32 ed[4096];
    int tid = threadIdx.x;
    ph[tid] = 0; pr[tid] = 0;
    cb[tid] = (tid < nb) ? cbase[tid] : 0;
    __syncthreads();
    int e0 = blockIdx.x * 4096;
#pragma unroll
    for (int j = 0; j < 16; ++j) {
        int i = e0 + j * 256 + tid;
        u32 p = 0xFFFFFFFFu;
        if (i < e) {
            int d = dst[i];
            p = ((u32)d << 16) | (u32)src[i];
            atomicAdd(&ph[d >> 8], 1);
        }
        ed[j * 256 + tid] = p;
    }
    __syncthreads();
    pb[tid] = (tid < nb && ph[tid]) ? atomicAdd(&cfill[tid], ph[tid]) : 0;
    __syncthreads();
#pragma unroll
    for (int j = 0; j < 16; ++j) {
        u32 p = ed[j * 256 + tid];
        if (p != 0xFFFFFFFFu) {
            int bk = p >> 24;
            int r = atomicAdd(&pr[bk], 1);
            tmp[cb[bk] + pb[bk] + r] = p;
        }
    }
}

__global__ __launch_bounds__(256) void passB_kernel(const u32* __restrict__ tmp,
                                                    const int* __restrict__ cbase,
                                                    int* __restrict__ rowptr,
                                                    float* __restrict__ invd,
                                                    int* __restrict__ srcs, int n) {
    __shared__ int h[256], loc[256], cnt2[256], sh[256];
    int b = blockIdx.x;
    int tid = threadIdx.x;
    int base = cbase[b];
    int cnt = cbase[b + 1] - base;
    int node0 = b << 8;
    h[tid] = 0; cnt2[tid] = 0;
    __syncthreads();
    for (int i = tid; i < cnt; i += 256)
        atomicAdd(&h[(tmp[base + i] >> 16) & 255], 1);
    __syncthreads();
    int c = h[tid];
    int x = c;
    sh[tid] = x; __syncthreads();
    for (int o = 1; o < 256; o <<= 1) {
        int y = (tid >= o) ? sh[tid - o] : 0;
        __syncthreads();
        x += y; sh[tid] = x; __syncthreads();
    }
    loc[tid] = x - c;
    int node = node0 + tid;
    if (node < n) {
        rowptr[node] = base + x - c;
        invd[node] = 1.0f / (float)(c > 0 ? c : 1);
    }
    __syncthreads();
    for (int i = tid; i < cnt; i += 256) {
        u32 p = tmp[base + i];
        int ln = (p >> 16) & 255;
        int r = atomicAdd(&cnt2[ln], 1);
        srcs[base + loc[ln] + r] = (int)(p & 0xffffu);
    }
}

// ---------------- mean aggregation: one wave per node, fp8 gather, bf16 mean out ----------------

__global__ __launch_bounds__(256) void agg_kernel(const u8* __restrict__ q,
                                                  u16* __restrict__ mb,
                                                  const int* __restrict__ rowptr,
                                                  const int* __restrict__ srcs,
                                                  const float* __restrict__ invd,
                                                  int n, int npad) {
    int gw = (blockIdx.x * 256 + threadIdx.x) >> 6;
    int lane = threadIdx.x & 63;
    int qd = lane >> 4;          // edge slot within group of 4
    int fl = lane & 15;          // 16B chunk within fp8 row
    if (gw >= npad) return;
    u16* orow = mb + (size_t)gw * 256;
    if (gw >= n) {
        if (lane < 16) {
            uint4 z; z.x = z.y = z.z = z.w = 0;
            uint4* p = (uint4*)(orow + lane * 16);
            p[0] = z; p[1] = z;
        }
        return;
    }
    int beg = rowptr[gw], end = rowptr[gw + 1];
    float a[16];
#pragma unroll
    for (int i = 0; i < 16; ++i) a[i] = 0.f;
    for (int base = beg; base < end; base += 64) {
        int cnt = end - base;
        if (cnt > 64) cnt = 64;
        int el = (lane < cnt) ? srcs[base + lane] : 0;
        int t = 0;
        for (; 4 * t + 8 <= cnt; t += 2) {
            int s0 = __shfl(el, 4 * t + qd);
            int s1 = __shfl(el, 4 * t + 4 + qd);
            uint4 v0 = *(const uint4*)(q + (size_t)s0 * 256 + fl * 16);
            uint4 v1 = *(const uint4*)(q + (size_t)s1 * 256 + fl * 16);
            acc16(a, v0);
            acc16(a, v1);
        }
        for (; 4 * t < cnt; ++t) {
            int ei = 4 * t + qd;
            int sj = __shfl(el, ei & 63);
            float m = (ei < cnt) ? 1.0f : 0.0f;
            uint4 v = *(const uint4*)(q + (size_t)sj * 256 + fl * 16);
            acc16m(a, v, m);
        }
    }
#pragma unroll
    for (int i = 0; i < 16; ++i) {
        a[i] += __shfl_xor(a[i], 16);
        a[i] += __shfl_xor(a[i], 32);
    }
    if (lane < 16) {
        float sc = invd[gw];
        uint4 o0, o1;
        o0.x = pack2(a[0] * sc, a[1] * sc);
        o0.y = pack2(a[2] * sc, a[3] * sc);
        o0.z = pack2(a[4] * sc, a[5] * sc);
        o0.w = pack2(a[6] * sc, a[7] * sc);
        o1.x = pack2(a[8] * sc, a[9] * sc);
        o1.y = pack2(a[10] * sc, a[11] * sc);
        o1.z = pack2(a[12] * sc, a[13] * sc);
        o1.w = pack2(a[14] * sc, a[15] * sc);
        uint4* p = (uint4*)(orow + lane * 16);
        p[0] = o0; p[1] = o1;
    }
}

// ---------------- fused GEMM: 128x128 tile, BK=64, seg-major LDS (conflict-free) ----------------
// A: rows from mb (k<256) then cur (k>=256), both [NPAD][256] bf16 row-major.
// B: wT layer slice [n=256][k=512] bf16 k-contiguous; block handles col half ch*128.
// LDS layout (both lA/lB): u16 idx = seg*1024 + row*8, seg=0..7 (8B segments of the
// 64-u16 k-chunk), row=0..127. Reader banks = 4*(lrow&7) -> 2-way only (free).
// Staged via global_load_lds width=16 (per-lane global addr, lane-contiguous dest).
// Epilogue writes bf16 h AND fp8 hq (replaces cvt_h). fin: dot wo, reduce, atomicAdd.

__global__ __launch_bounds__(256) void gemm_kernel(const u16* __restrict__ mb,
                                                   const u16* __restrict__ cur,
                                                   const u16* __restrict__ wT,
                                                   u16* __restrict__ hout,
                                                   u8* __restrict__ hq,
                                                   const float* __restrict__ wo,
                                                   const float* __restrict__ bo,
                                                   float* __restrict__ out,
                                                   int n, int sig, int fin) {
    __shared__ u16 lA[8192];   // 16 KB
    __shared__ u16 lB[8192];   // 16 KB
    int tid = threadIdx.x;
    int bid = blockIdx.x;
    int ch = bid & 1;
    int r0 = (bid >> 1) * 128;
    int c0 = ch * 128;
    int lane = tid & 63;
    int w = tid >> 6;
    int wrow = w >> 1, wcol = w & 1;
    int lrow = lane & 15, quad = lane >> 4;

    f32x4 acc[4][4] = {};

    for (int ks = 0; ks < 8; ++ks) {
        const u16* sA = (ks < 4) ? mb : cur;
        int kk = (ks & 3) * 64;              // u16 offset within the 256-wide source
        __syncthreads();
        // 32 staging instructions: c=0..15 -> lA, c=16..31 -> lB; wave w does c=w*8..w*8+7
#pragma unroll
        for (int i = 0; i < 8; ++i) {
            int c = w * 8 + i;
            if (c < 16) {
                int s = c * 64 + lane;       // slot 0..1023
                int row = s & 127, seg = s >> 7;
                const u16* g = sA + (size_t)(r0 + row) * 256 + kk + seg * 8;
                __builtin_amdgcn_global_load_lds(
                    (const __attribute__((address_space(1))) u32*)g,
                    (__attribute__((address_space(3))) u32*)(lA + (size_t)seg * 1024 + row * 8), 16, 0, 0);
            } else {
                int s = (c - 16) * 64 + lane;
                int row = s & 127, seg = s >> 7;
                const u16* g = wT + (size_t)(c0 + row) * 512 + ks * 64 + seg * 8;
                __builtin_amdgcn_global_load_lds(
                    (const __attribute__((address_space(1))) u32*)g,
                    (__attribute__((address_space(3))) u32*)(lB + (size_t)seg * 1024 + row * 8), 16, 0, 0);
            }
        }
        __syncthreads();

#pragma unroll
        for (int u = 0; u < 2; ++u) {
            short8 a[4], b[4];
#pragma unroll
            for (int rt = 0; rt < 4; ++rt) {
                int row = wrow * 64 + rt * 16 + lrow;
                a[rt] = *(const short8*)(lA + (size_t)(u * 4 + quad) * 1024 + row * 8);
            }
#pragma unroll
            for (int ct = 0; ct < 4; ++ct) {
                int col = wcol * 64 + ct * 16 + lrow;
                b[ct] = *(const short8*)(lB + (size_t)(u * 4 + quad) * 1024 + col * 8);
            }
#pragma unroll
            for (int rt = 0; rt < 4; ++rt)
#pragma unroll
                for (int ct = 0; ct < 4; ++ct)
                    acc[rt][ct] = __builtin_amdgcn_mfma_f32_16x16x32_bf16(a[rt], b[ct], acc[rt][ct], 0, 0, 0);
        }
    }

    if (!fin) {
#pragma unroll
        for (int rt = 0; rt < 4; ++rt) {
#pragma unroll
            for (int r = 0; r < 4; ++r) {
                int row = r0 + wrow * 64 + rt * 16 + quad * 4 + r;
#pragma unroll
                for (int ct = 0; ct < 4; ++ct) {
                    float v = acc[rt][ct][r];
                    if (sig) v = 1.0f / (1.0f + __expf(-v));
                    int col = c0 + wcol * 64 + ct * 16 + lrow;
                    hout[(size_t)row * 256 + col] = f2bf(v);
                    hq[(size_t)row * 256 + col] = f2fp8(v);
                }
            }
        }
    } else {
        float bo0 = bo[0];
        float wv[4];
#pragma unroll
        for (int ct = 0; ct < 4; ++ct) wv[ct] = wo[c0 + wcol * 64 + ct * 16 + lrow];
#pragma unroll
        for (int rt = 0; rt < 4; ++rt) {
#pragma unroll
            for (int r = 0; r < 4; ++r) {
                float s = 0.f;
#pragma unroll
                for (int ct = 0; ct < 4; ++ct) {
                    float v = acc[rt][ct][r];
                    v = 1.0f / (1.0f + __expf(-v));
                    s += v * wv[ct];
                }
                s += __shfl_xor(s, 1);
                s += __shfl_xor(s, 2);
                s += __shfl_xor(s, 4);
                s += __shfl_xor(s, 8);
                if (lrow == 0) {
                    int row = r0 + wrow * 64 + rt * 16 + quad * 4 + r;
                    if (row < n) atomicAdd(&out[row], s + ((ch == 0 && wcol == 0) ? bo0 : 0.f));
                }
            }
        }
    }
}

// ---------------- launch ----------------

extern "C" void kernel_launch(void* const* d_in, const int* in_sizes, int n_in,
                              void* d_out, int out_size, void* d_ws, size_t ws_size,
                              hipStream_t stream) {
    const float* x  = (const float*)d_in[0];
    const int*   ei = (const int*)d_in[1];
    const float* WA = (const float*)d_in[2];
    const float* WB = (const float*)d_in[3];
    const float* As = (const float*)d_in[4];
    const float* Bs = (const float*)d_in[5];
    const float* Wo = (const float*)d_in[6];
    const float* bo = (const float*)d_in[7];
    float* out = (float*)d_out;

    const int H = 256;
    int N = in_sizes[0] / H;
    int E = in_sizes[1] / 2;
    int L = in_sizes[4] / (H * H);
    int NPAD = (N + 127) & ~127;
    int NB = (N + 255) >> 8;           // coarse buckets (requires N <= 65536)

    char* wsp = (char*)d_ws;
    size_t off = 0;
    auto alloc = [&](size_t b) { size_t o = off; off += (b + 255) & ~(size_t)255; return o; };
    int*   rowptr = (int*)(wsp + alloc((size_t)(NPAD + 1) * 4));
    int*   ccnt   = (int*)(wsp + alloc(1024));
    int*   cbase  = (int*)(wsp + alloc(1032 + 256));
    int*   cfill  = (int*)(wsp + alloc(1024));
    float* invd   = (float*)(wsp + alloc((size_t)NPAD * 4));
    int*   srcs   = (int*)(wsp + alloc((size_t)E * 4));
    u16*   xb     = (u16*)(wsp + alloc((size_t)NPAD * H * 2));
    u16*   h0     = (u16*)(wsp + alloc((size_t)NPAD * H * 2));
    u16*   h1     = (u16*)(wsp + alloc((size_t)NPAD * H * 2));
    u16*   mb     = (u16*)(wsp + alloc((size_t)NPAD * H * 2));
    u8*    xq     = (u8*)(wsp + alloc((size_t)NPAD * H));
    u8*    hq     = (u8*)(wsp + alloc((size_t)NPAD * H));
    u16*   wT     = (u16*)(wsp + alloc((size_t)(L + 1) * 512 * 256 * 2));
    // tmp (packed coarse-sorted edges) aliases mb: dead until first agg writes mb
    u32*   tmp    = (u32*)mb;

    const int* esrc = ei;
    const int* edst = ei + E;

    hipMemsetAsync(ccnt, 0, 1024, stream);
    hipMemsetAsync(cfill, 0, 1024, stream);
    hipMemsetAsync(out, 0, (size_t)N * 4, stream);

    int gridE = (E + 4095) / 4096;
    cvt_x_kernel<<<NPAD / 4, 256, 0, stream>>>(x, xb, (u32*)xq, N);
    cvt_w_kernel<<<((L + 1) * 512 * 256 + 255) / 256, 256, 0, stream>>>(WA, WB, As, Bs, wT, L + 1);
    hist_kernel<<<gridE, 256, 0, stream>>>(edst, ccnt, E, NB);
    scan_coarse_kernel<<<1, 256, 0, stream>>>(ccnt, cbase, rowptr, NB, N, E);
    passA_kernel<<<gridE, 256, 0, stream>>>(esrc, edst, cbase, cfill, tmp, E, NB);
    passB_kernel<<<NB, 256, 0, stream>>>(tmp, cbase, rowptr, invd, srcs, N);

    const u16* cur = xb;
    const u8*  curq = xq;
    for (int s = 0; s <= L; ++s) {
        int fin = (s == L) ? 1 : 0;
        u16* nxt = (s & 1) ? h1 : h0;
        agg_kernel<<<NPAD / 4, 256, 0, stream>>>(curq, mb, rowptr, srcs, invd, N, NPAD);
        gemm_kernel<<<(NPAD / 128) * 2, 256, 0, stream>>>(mb, cur, wT + (size_t)s * 512 * 256,
                                                          nxt, hq, Wo, bo, out, N,
                                                          s > 0 ? 1 : 0, fin);
        if (!fin) {
            cur = nxt;
            curq = hq;
        }
    }
}

// Round 9
// 395.031 us; speedup vs baseline: 1.9347x; 1.0228x over previous
//
#include <hip/hip_runtime.h>

typedef unsigned char u8;
typedef unsigned short u16;
typedef unsigned int u32;
typedef __attribute__((ext_vector_type(8))) short short8;
typedef __attribute__((ext_vector_type(4))) float f32x4;
typedef __attribute__((ext_vector_type(2))) float f32x2;

__device__ __forceinline__ float bf2f(u16 u) {
    return __uint_as_float(((u32)u) << 16);
}
__device__ __forceinline__ u16 f2bf(float f) {
    u32 u = __float_as_uint(f);
    u += 0x7fff + ((u >> 16) & 1);   // round-to-nearest-even
    return (u16)(u >> 16);
}
__device__ __forceinline__ u32 pack2(float a, float b) {
    return (u32)f2bf(a) | ((u32)f2bf(b) << 16);
}
__device__ __forceinline__ u32 pk_fp8x4(float f0, float f1, float f2, float f3) {
    int w = __builtin_amdgcn_cvt_pk_fp8_f32(f0, f1, 0, false);
    w = __builtin_amdgcn_cvt_pk_fp8_f32(f2, f3, w, true);
    return (u32)w;
}
__device__ __forceinline__ u8 f2fp8(float f) {
    return (u8)(__builtin_amdgcn_cvt_pk_fp8_f32(f, f, 0, false) & 0xff);
}
__device__ __forceinline__ void acc4(float* a, u32 w) {
    f32x2 lo = __builtin_amdgcn_cvt_pk_f32_fp8((int)w, false);
    f32x2 hi = __builtin_amdgcn_cvt_pk_f32_fp8((int)w, true);
    a[0] += lo.x; a[1] += lo.y; a[2] += hi.x; a[3] += hi.y;
}
__device__ __forceinline__ void acc4m(float* a, u32 w, float m) {
    f32x2 lo = __builtin_amdgcn_cvt_pk_f32_fp8((int)w, false);
    f32x2 hi = __builtin_amdgcn_cvt_pk_f32_fp8((int)w, true);
    a[0] += m * lo.x; a[1] += m * lo.y; a[2] += m * hi.x; a[3] += m * hi.y;
}
__device__ __forceinline__ void acc16(float* a, uint4 v) {
    acc4(a + 0, v.x); acc4(a + 4, v.y); acc4(a + 8, v.z); acc4(a + 12, v.w);
}
__device__ __forceinline__ void acc16m(float* a, uint4 v, float m) {
    acc4m(a + 0, v.x, m); acc4m(a + 4, v.y, m); acc4m(a + 8, v.z, m); acc4m(a + 12, v.w, m);
}

// ---------------- conversions ----------------

// x fp32 -> xb bf16 [NPAD][256] (zero-padded)
__global__ void cvt_x_kernel(const float* __restrict__ x, u16* __restrict__ xb, int n) {
    int i = blockIdx.x * 256 + threadIdx.x;   // group of 4 elements
    int row = i >> 6;
    ushort4 o;
    if (row < n) {
        float4 v = ((const float4*)x)[i];
        o.x = f2bf(v.x); o.y = f2bf(v.y); o.z = f2bf(v.z); o.w = f2bf(v.w);
    } else {
        o.x = o.y = o.z = o.w = 0;
    }
    ((ushort4*)xb)[i] = o;
}

// wT layout: [layer][n=512][k=256] bf16, k-contiguous. Output col n: n<256 -> A[:,n],
// n>=256 -> B[:,n-256]; weights stored [in,out] so element = W[k*256 + col].
__global__ void cvt_w_kernel(const float* __restrict__ WA, const float* __restrict__ WB,
                             const float* __restrict__ As, const float* __restrict__ Bs,
                             u16* __restrict__ wT, int nlayers) {
    int i = blockIdx.x * 256 + threadIdx.x;
    const int per = 512 * 256;
    if (i >= nlayers * per) return;
    int l = i / per;
    int rem = i - l * per;
    int nn = rem >> 8;        // 0..511
    int k = rem & 255;        // 0..255
    const float* Aw = (l == 0) ? WA : As + (size_t)(l - 1) * 65536;
    const float* Bw = (l == 0) ? WB : Bs + (size_t)(l - 1) * 65536;
    float v = (nn < 256) ? Aw[(size_t)k * 256 + nn] : Bw[(size_t)k * 256 + (nn - 256)];
    wT[i] = f2bf(v);
}

// ---------------- CSR build: two-level counting sort ----------------
// Requires N <= 65536; coarse bucket b covers nodes [b*256, b*256+256).

__global__ __launch_bounds__(256) void hist_kernel(const int* __restrict__ dst,
                                                   int* __restrict__ ccnt, int e, int nb) {
    __shared__ int h[256];
    int tid = threadIdx.x;
    h[tid] = 0;
    __syncthreads();
    int e0 = blockIdx.x * 4096;
#pragma unroll
    for (int j = 0; j < 16; ++j) {
        int i = e0 + j * 256 + tid;
        if (i < e) atomicAdd(&h[dst[i] >> 8], 1);
    }
    __syncthreads();
    if (tid < nb) {
        int v = h[tid];
        if (v) atomicAdd(&ccnt[tid], v);
    }
}

__global__ __launch_bounds__(256) void scan_coarse_kernel(const int* __restrict__ ccnt,
                                                          int* __restrict__ cbase,
                                                          int* __restrict__ rowptr,
                                                          int nb, int n, int e) {
    __shared__ int sh[256];
    int t = threadIdx.x;
    int v = (t < nb) ? ccnt[t] : 0;
    int x = v;
    sh[t] = x; __syncthreads();
    for (int o = 1; o < 256; o <<= 1) {
        int y = (t >= o) ? sh[t - o] : 0;
        __syncthreads();
        x += y; sh[t] = x; __syncthreads();
    }
    if (t < nb) cbase[t] = x - v;
    if (t == 0) { cbase[nb] = e; rowptr[n] = e; }
}

__global__ __launch_bounds__(256) void passA_kernel(const int* __restrict__ src,
                                                    const int* __restrict__ dst,
                                                    const int* __restrict__ cbase,
                                                    int* __restrict__ cfill,
                                                    u32* __restrict__ tmp, int e, int nb) {
    __shared__ int ph[256], pb[256], pr[256], cb[256];
    __shared__ u32 ed[4096];
    int tid = threadIdx.x;
    ph[tid] = 0; pr[tid] = 0;
    cb[tid] = (tid < nb) ? cbase[tid] : 0;
    __syncthreads();
    int e0 = blockIdx.x * 4096;
#pragma unroll
    for (int j = 0; j < 16; ++j) {
        int i = e0 + j * 256 + tid;
        u32 p = 0xFFFFFFFFu;
        if (i < e) {
            int d = dst[i];
            p = ((u32)d << 16) | (u32)src[i];
            atomicAdd(&ph[d >> 8], 1);
        }
        ed[j * 256 + tid] = p;
    }
    __syncthreads();
    pb[tid] = (tid < nb && ph[tid]) ? atomicAdd(&cfill[tid], ph[tid]) : 0;
    __syncthreads();
#pragma unroll
    for (int j = 0; j < 16; ++j) {
        u32 p = ed[j * 256 + tid];
        if (p != 0xFFFFFFFFu) {
            int bk = p >> 24;
            int r = atomicAdd(&pr[bk], 1);
            tmp[cb[bk] + pb[bk] + r] = p;
        }
    }
}

__global__ __launch_bounds__(256) void passB_kernel(const u32* __restrict__ tmp,
                                                    const int* __restrict__ cbase,
                                                    int* __restrict__ rowptr,
                                                    float* __restrict__ invd,
                                                    int* __restrict__ srcs, int n) {
    __shared__ int h[256], loc[256], cnt2[256], sh[256];
    int b = blockIdx.x;
    int tid = threadIdx.x;
    int base = cbase[b];
    int cnt = cbase[b + 1] - base;
    int node0 = b << 8;
    h[tid] = 0; cnt2[tid] = 0;
    __syncthreads();
    for (int i = tid; i < cnt; i += 256)
        atomicAdd(&h[(tmp[base + i] >> 16) & 255], 1);
    __syncthreads();
    int c = h[tid];
    int x = c;
    sh[tid] = x; __syncthreads();
    for (int o = 1; o < 256; o <<= 1) {
        int y = (tid >= o) ? sh[tid - o] : 0;
        __syncthreads();
        x += y; sh[tid] = x; __syncthreads();
    }
    loc[tid] = x - c;
    int node = node0 + tid;
    if (node < n) {
        rowptr[node] = base + x - c;
        invd[node] = 1.0f / (float)(c > 0 ? c : 1);
    }
    __syncthreads();
    for (int i = tid; i < cnt; i += 256) {
        u32 p = tmp[base + i];
        int ln = (p >> 16) & 255;
        int r = atomicAdd(&cnt2[ln], 1);
        srcs[base + loc[ln] + r] = (int)(p & 0xffffu);
    }
}

// ---------------- aggregation + layer finish: one wave per node ----------------
// node i: v = invd[i] * sum_j GA[src_j]  + GB[i];  if sig: v = sigmoid(v).
// !fin: write h row (bf16). fin: out[i] = dot(v, wo) + bo.

__global__ __launch_bounds__(256) void agg_kernel(const u8* __restrict__ GA,
                                                  const u16* __restrict__ GB,
                                                  u16* __restrict__ hout,
                                                  const int* __restrict__ rowptr,
                                                  const int* __restrict__ srcs,
                                                  const float* __restrict__ invd,
                                                  const float* __restrict__ wo,
                                                  const float* __restrict__ bo,
                                                  float* __restrict__ out,
                                                  int n, int npad, int sig, int fin) {
    int gw = (blockIdx.x * 256 + threadIdx.x) >> 6;
    int lane = threadIdx.x & 63;
    int qd = lane >> 4;          // edge slot within group of 4
    int fl = lane & 15;          // 16B chunk within fp8 row
    if (gw >= npad) return;
    if (gw >= n) {
        if (!fin && lane < 16) {
            uint4 z; z.x = z.y = z.z = z.w = 0;
            uint4* p = (uint4*)(hout + (size_t)gw * 256 + lane * 16);
            p[0] = z; p[1] = z;
        }
        return;
    }
    int beg = rowptr[gw], end = rowptr[gw + 1];
    float a[16];
#pragma unroll
    for (int i = 0; i < 16; ++i) a[i] = 0.f;
    for (int base = beg; base < end; base += 64) {
        int cnt = end - base;
        if (cnt > 64) cnt = 64;
        int el = (lane < cnt) ? srcs[base + lane] : 0;
        int t = 0;
        for (; 4 * t + 8 <= cnt; t += 2) {
            int s0 = __shfl(el, 4 * t + qd);
            int s1 = __shfl(el, 4 * t + 4 + qd);
            uint4 v0 = *(const uint4*)(GA + (size_t)s0 * 256 + fl * 16);
            uint4 v1 = *(const uint4*)(GA + (size_t)s1 * 256 + fl * 16);
            acc16(a, v0);
            acc16(a, v1);
        }
        for (; 4 * t < cnt; ++t) {
            int ei = 4 * t + qd;
            int sj = __shfl(el, ei & 63);
            float m = (ei < cnt) ? 1.0f : 0.0f;
            uint4 v = *(const uint4*)(GA + (size_t)sj * 256 + fl * 16);
            acc16m(a, v, m);
        }
    }
#pragma unroll
    for (int i = 0; i < 16; ++i) {
        a[i] += __shfl_xor(a[i], 16);
        a[i] += __shfl_xor(a[i], 32);
    }
    if (lane < 16) {
        float sc = invd[gw];
        const u16* gb = GB + (size_t)gw * 256 + lane * 16;
        uint4 g0 = ((const uint4*)gb)[0];
        uint4 g1 = ((const uint4*)gb)[1];
        u32 gp[8] = {g0.x, g0.y, g0.z, g0.w, g1.x, g1.y, g1.z, g1.w};
        float v[16];
#pragma unroll
        for (int j = 0; j < 8; ++j) {
            v[2 * j]     = a[2 * j] * sc     + bf2f(gp[j] & 0xffff);
            v[2 * j + 1] = a[2 * j + 1] * sc + bf2f(gp[j] >> 16);
        }
        if (sig) {
#pragma unroll
            for (int i = 0; i < 16; ++i) v[i] = 1.0f / (1.0f + __expf(-v[i]));
        }
        if (!fin) {
            uint4 o0, o1;
            o0.x = pack2(v[0], v[1]);   o0.y = pack2(v[2], v[3]);
            o0.z = pack2(v[4], v[5]);   o0.w = pack2(v[6], v[7]);
            o1.x = pack2(v[8], v[9]);   o1.y = pack2(v[10], v[11]);
            o1.z = pack2(v[12], v[13]); o1.w = pack2(v[14], v[15]);
            uint4* p = (uint4*)(hout + (size_t)gw * 256 + lane * 16);
            p[0] = o0; p[1] = o1;
        } else {
            const float4* wv = (const float4*)(wo + lane * 16);
            float s = 0.f;
#pragma unroll
            for (int j = 0; j < 4; ++j) {
                float4 wf = wv[j];
                s += v[4 * j] * wf.x + v[4 * j + 1] * wf.y +
                     v[4 * j + 2] * wf.z + v[4 * j + 3] * wf.w;
            }
            s += __shfl_xor(s, 1);
            s += __shfl_xor(s, 2);
            s += __shfl_xor(s, 4);
            s += __shfl_xor(s, 8);
            if (lane == 0) out[gw] = s + bo[0];
        }
    }
}

// ---------------- GEMM: G = h @ [A|B], M=NPAD K=256 N=512 ----------------
// 128x128 tile (grid NPAD/128 * 4), BK=32, double-buffered single-barrier K-loop,
// seg-major LDS (u16 idx = seg*1024 + row*8) -> 2-way max bank aliasing (free).
// Col-quarters 0,1 -> GA fp8 [NPAD][256]; quarters 2,3 -> GB bf16 [NPAD][256].

__global__ __launch_bounds__(256) void gemm_kernel(const u16* __restrict__ hsrc,
                                                   const u16* __restrict__ wT,
                                                   u8* __restrict__ GA,
                                                   u16* __restrict__ GB) {
    __shared__ u16 lA[2][4096];   // 8 KB each
    __shared__ u16 lB[2][4096];
    int tid = threadIdx.x;
    int bid = blockIdx.x;
    int cq = bid & 3;
    int r0 = (bid >> 2) << 7;
    int c0 = cq << 7;
    int lane = tid & 63;
    int w = tid >> 6;
    int wrow = w >> 1, wcol = w & 1;
    int lrow = lane & 15, quad = lane >> 4;

    auto stage = [&](int ks, int b) {
#pragma unroll
        for (int i = 0; i < 2; ++i) {
            int s = (w * 2 + i) * 64 + lane;   // 0..511
            int row = s & 127, seg = s >> 7;
            const u16* g = hsrc + (size_t)(r0 + row) * 256 + ks * 32 + seg * 8;
            __builtin_amdgcn_global_load_lds(
                (const __attribute__((address_space(1))) u32*)g,
                (__attribute__((address_space(3))) u32*)(&lA[b][(size_t)seg * 1024 + row * 8]), 16, 0, 0);
            const u16* g2 = wT + (size_t)(c0 + row) * 256 + ks * 32 + seg * 8;
            __builtin_amdgcn_global_load_lds(
                (const __attribute__((address_space(1))) u32*)g2,
                (__attribute__((address_space(3))) u32*)(&lB[b][(size_t)seg * 1024 + row * 8]), 16, 0, 0);
        }
    };

    f32x4 acc[4][4] = {};
    stage(0, 0);
    for (int ks = 0; ks < 8; ++ks) {
        __syncthreads();               // waits for stage(ks); reads of buf^1 finished last iter
        if (ks < 7) stage(ks + 1, (ks + 1) & 1);
        int buf = ks & 1;
        short8 a[4], b[4];
#pragma unroll
        for (int rt = 0; rt < 4; ++rt) {
            int row = wrow * 64 + rt * 16 + lrow;
            a[rt] = *(const short8*)(&lA[buf][(size_t)quad * 1024 + row * 8]);
        }
#pragma unroll
        for (int ct = 0; ct < 4; ++ct) {
            int col = wcol * 64 + ct * 16 + lrow;
            b[ct] = *(const short8*)(&lB[buf][(size_t)quad * 1024 + col * 8]);
        }
#pragma unroll
        for (int rt = 0; rt < 4; ++rt)
#pragma unroll
            for (int ct = 0; ct < 4; ++ct)
                acc[rt][ct] = __builtin_amdgcn_mfma_f32_16x16x32_bf16(a[rt], b[ct], acc[rt][ct], 0, 0, 0);
    }

    if (c0 < 256) {   // GA fp8
#pragma unroll
        for (int rt = 0; rt < 4; ++rt) {
#pragma unroll
            for (int r = 0; r < 4; ++r) {
                int row = r0 + wrow * 64 + rt * 16 + quad * 4 + r;
#pragma unroll
                for (int ct = 0; ct < 4; ++ct) {
                    int col = c0 + wcol * 64 + ct * 16 + lrow;
                    GA[(size_t)row * 256 + col] = f2fp8(acc[rt][ct][r]);
                }
            }
        }
    } else {          // GB bf16
        int cb = c0 - 256;
#pragma unroll
        for (int rt = 0; rt < 4; ++rt) {
#pragma unroll
            for (int r = 0; r < 4; ++r) {
                int row = r0 + wrow * 64 + rt * 16 + quad * 4 + r;
#pragma unroll
                for (int ct = 0; ct < 4; ++ct) {
                    int col = cb + wcol * 64 + ct * 16 + lrow;
                    GB[(size_t)row * 256 + col] = f2bf(acc[rt][ct][r]);
                }
            }
        }
    }
}

// ---------------- launch ----------------

extern "C" void kernel_launch(void* const* d_in, const int* in_sizes, int n_in,
                              void* d_out, int out_size, void* d_ws, size_t ws_size,
                              hipStream_t stream) {
    const float* x  = (const float*)d_in[0];
    const int*   ei = (const int*)d_in[1];
    const float* WA = (const float*)d_in[2];
    const float* WB = (const float*)d_in[3];
    const float* As = (const float*)d_in[4];
    const float* Bs = (const float*)d_in[5];
    const float* Wo = (const float*)d_in[6];
    const float* bo = (const float*)d_in[7];
    float* out = (float*)d_out;

    const int H = 256;
    int N = in_sizes[0] / H;
    int E = in_sizes[1] / 2;
    int L = in_sizes[4] / (H * H);
    int NPAD = (N + 127) & ~127;
    int NB = (N + 255) >> 8;           // coarse buckets (requires N <= 65536)

    char* wsp = (char*)d_ws;
    size_t off = 0;
    auto alloc = [&](size_t b) { size_t o = off; off += (b + 255) & ~(size_t)255; return o; };
    int*   rowptr = (int*)(wsp + alloc((size_t)(NPAD + 1) * 4));
    int*   ccnt   = (int*)(wsp + alloc(1024));
    int*   cbase  = (int*)(wsp + alloc(1032 + 256));
    int*   cfill  = (int*)(wsp + alloc(1024));
    float* invd   = (float*)(wsp + alloc((size_t)NPAD * 4));
    int*   srcs   = (int*)(wsp + alloc((size_t)E * 4));
    u16*   xb     = (u16*)(wsp + alloc((size_t)NPAD * H * 2));
    u16*   h1     = (u16*)(wsp + alloc((size_t)NPAD * H * 2));
    u16*   h2     = (u16*)(wsp + alloc((size_t)NPAD * H * 2));
    u8*    GA     = (u8*)(wsp + alloc((size_t)NPAD * H));
    u16*   GB     = (u16*)(wsp + alloc((size_t)NPAD * H * 2));
    u16*   wT     = (u16*)(wsp + alloc((size_t)(L + 1) * 512 * 256 * 2));
    // tmp (packed coarse-sorted edges) aliases GA: dead until first gemm writes GA
    u32*   tmp    = (u32*)GA;

    const int* esrc = ei;
    const int* edst = ei + E;

    hipMemsetAsync(ccnt, 0, 1024, stream);
    hipMemsetAsync(cfill, 0, 1024, stream);

    int gridE = (E + 4095) / 4096;
    cvt_x_kernel<<<NPAD / 4, 256, 0, stream>>>(x, xb, N);
    cvt_w_kernel<<<((L + 1) * 512 * 256 + 255) / 256, 256, 0, stream>>>(WA, WB, As, Bs, wT, L + 1);
    hist_kernel<<<gridE, 256, 0, stream>>>(edst, ccnt, E, NB);
    scan_coarse_kernel<<<1, 256, 0, stream>>>(ccnt, cbase, rowptr, NB, N, E);
    passA_kernel<<<gridE, 256, 0, stream>>>(esrc, edst, cbase, cfill, tmp, E, NB);
    passB_kernel<<<NB, 256, 0, stream>>>(tmp, cbase, rowptr, invd, srcs, N);

    const u16* cur = xb;
    for (int s = 0; s <= L; ++s) {
        int fin = (s == L) ? 1 : 0;
        int sig = (s > 0) ? 1 : 0;     // layer 0 (proj_in) has no activation
        u16* nxt = (s & 1) ? h2 : h1;
        gemm_kernel<<<(NPAD / 128) * 4, 256, 0, stream>>>(cur, wT + (size_t)s * 512 * 256, GA, GB);
        agg_kernel<<<NPAD / 4, 256, 0, stream>>>(GA, GB, nxt, rowptr, srcs, invd,
                                                 Wo, bo, out, N, NPAD, sig, fin);
        cur = nxt;
    }
}